// Round 14
// baseline (5541.478 us; speedup 1.0000x reference)
//
#include <hip/hip_runtime.h>

#define TSTEPS 2048
#define VDIM 128
#define FDIM 512

typedef __attribute__((ext_vector_type(8))) _Float16 half8;
typedef __attribute__((ext_vector_type(4))) _Float16 half4;
typedef __attribute__((ext_vector_type(4))) float floatx4;
typedef unsigned long long u64;
typedef __attribute__((ext_vector_type(2))) unsigned long long u64x2;

// ws layout (bytes):
//   [0,512K)        WH: f16, A-frag order [chunk32][kk16][lane64][e8]
//   [1M,1M+128K)    r parity-0: [g8][kk16][lane64][e8] f16 (16KB/group)
//   [1M+128K,+256K) r parity-1: same
#define WS_WH 0
#define WS_R  (1024u * 1024u)

// Pre-swizzle W (fp32 row-major [j][k]) into A-frag order, single f16.
// A-frag (16x16x32 f16): lane l holds row (l&15), k = kk*32 + (l>>4)*8 + e.
__global__ __launch_bounds__(256) void rnn_prep(const float* __restrict__ W,
                                                _Float16* __restrict__ WH) {
  int tid = blockIdx.x * 256 + threadIdx.x;   // 32 chunks * 16 kk * 64 lanes
  int c  = tid >> 10;
  int kk = (tid >> 6) & 15;
  int l  = tid & 63;
  int j  = 16 * c + (l & 15);
  int k0 = kk * 32 + (l >> 4) * 8;
  const float* src = W + j * FDIM + k0;
  half8 vh;
#pragma unroll
  for (int e = 0; e < 8; ++e) vh[e] = (_Float16)src[e];
  *(half8*)(WH + (size_t)tid * 8) = vh;
}

// 32 WGs = 8 row-groups (g) x 4 slices (s), 768 thr = 12 waves, ROLE-SPLIT:
//   waves 0-7  = POLLERS: R9's exact poll (2 chunks each, single asm block
//                loads+vmcnt(0), tag fold), stage into LDS, barrier.  They
//                run one iteration AHEAD: while computers run compute(t),
//                pollers spin for r(t+1) -> detection overlaps compute.
//   waves 8-11 = COMPUTERS: 2 W-tiles each (128 regs, R13-proven), read the
//                staged r-tile from LDS (4x16=64 ds_read_b128 vs R9's 128),
//                MFMA, tanh, IC write-through store of r(t+1).
// Protocol (proven R4/R9): tag-in-data, tau(t)=(t>>1)&1 in every f16 LSB.
// One barrier per iteration pairs stage(t) with compute(t); barrier counts
// match between roles.  WAR safety: LDS buffer parity + barrier ordering;
// global 2-buffer safety by the R4 detection-before-store induction.
__global__ void __launch_bounds__(768, 1)
rnn_main(const float* __restrict__ X, const float* __restrict__ bvec,
         const _Float16* __restrict__ WH,
         _Float16* __restrict__ rbase, float* __restrict__ out) {
  __shared__ _Float16 lds[2][8192];           // 16KB per step-parity
  const int g  = blockIdx.x & 7;
  const int s  = blockIdx.x >> 3;
  const int w  = threadIdx.x >> 6;            // 0..11
  const int l  = threadIdx.x & 63;
  const u64 TAGM = 0x0001000100010001ULL;

  if (w < 8) {
    // ================= POLLER wave =================
    const int pcB = (2 * w) * 1024 + l * 16;  // own chunks 2w, 2w+1
    int budget = 4000000;
    for (int t = 0; t < TSTEPS; ++t) {
      const char* p0 = (const char*)rbase + (size_t)(t & 1) * (128 * 1024)
                     + (size_t)g * 16384 + pcB;
      const int wantbit = (t >> 1) & 1;
      u64x2 f0, f1;
      for (;;) {
        asm volatile(
          "global_load_dwordx4 %0, %2, off sc0 sc1\n\t"
          "global_load_dwordx4 %1, %2, off offset:1024 sc0 sc1\n\t"
          "s_waitcnt vmcnt(0)"
          : "=&v"(f0), "=&v"(f1) : "v"(p0) : "memory");
        int ok;
        if (wantbit) {
          u64 m = (f0[0] & f0[1]) & (f1[0] & f1[1]);
          ok = ((~m) & TAGM) == 0;
        } else {
          u64 m = (f0[0] | f0[1]) | (f1[0] | f1[1]);
          ok = (m & TAGM) == 0;
        }
        if (__all(ok)) break;
        if (--budget < 0) break;
      }
      // stage own 2 chunks into lds[t&1] (linear frag order, conflict-free)
      char* lp = (char*)lds[t & 1];
      *(u64x2*)(lp + pcB) = f0;
      *(u64x2*)(lp + pcB + 1024) = f1;
      __syncthreads();                        // pairs with computer's top sync
    }
  } else {
    // ================= COMPUTER wave =================
    const int cw = w - 8;                     // 0..3
    const int c0 = 8 * cw + s;                // 2 feature chunks (32 feats)
    const int c1 = 8 * cw + 4 + s;
    const int lr = l & 15;                    // D col = group-local state row
    const int lg = l >> 4;
    const int jb0 = 16 * c0 + lg * 4;
    const int jb1 = 16 * c1 + lg * 4;

    // persistent W fragments: 2 chunks x 16 kk = 128 regs
    half8 wh0[16], wh1[16];
#pragma unroll
    for (int kk = 0; kk < 16; ++kk) {
      wh0[kk] = ((const half8*)WH)[(c0 * 16 + kk) * 64 + l];
      wh1[kk] = ((const half8*)WH)[(c1 * 16 + kk) * 64 + l];
      asm volatile("" : "+v"(wh0[kk]), "+v"(wh1[kk]));
    }

    const floatx4 bv0 = *(const floatx4*)(bvec + jb0);
    const floatx4 bv1 = *(const floatx4*)(bvec + jb1);
    const bool vis0 = (c0 < 8), vis1 = (c1 < 8);
    const bool diag0 = (c0 == g), diag1 = (c1 == g);
    const int so0 = ((jb0 >> 5) << 9) + ((((jb0 >> 3) & 3) << 4) + lr) * 8 + (jb0 & 7);
    const int so1 = ((jb1 >> 5) << 9) + ((((jb1 >> 3) & 3) << 4) + lr) * 8 + (jb1 & 7);

    for (int t = 0; t < TSTEPS; ++t) {
      __syncthreads();                        // r(t) staged in lds[t&1]
      const char* lp = (const char*)lds[t & 1];

      floatx4 xv0 = {0.f,0.f,0.f,0.f}, xv1 = {0.f,0.f,0.f,0.f};
      if (vis0) xv0 = *(const floatx4*)(X + t * VDIM + jb0);
      if (vis1) xv1 = *(const floatx4*)(X + t * VDIM + jb1);

      // MFMA: D[j][i] = sum_k W[j,k] r[i,k]; each b128 feeds both tiles
      floatx4 a0 = {0.f,0.f,0.f,0.f}, a1 = {0.f,0.f,0.f,0.f};
#pragma unroll
      for (int kk = 0; kk < 16; ++kk) {
        half8 b = *(const half8*)(lp + kk * 1024 + l * 16);
        a0 = __builtin_amdgcn_mfma_f32_16x16x32_f16(wh0[kk], b, a0, 0, 0, 0);
        a1 = __builtin_amdgcn_mfma_f32_16x16x32_f16(wh1[kk], b, a1, 0, 0, 0);
      }

      // epilogue: combine, blend, tanh, tag, publish r(t+1), both chunks
      const bool last = (t == TSTEPS - 1);
      union { half4 h; u64 u; } pk0, pk1; pk0.u = 0; pk1.u = 0;
#pragma unroll
      for (int v = 0; v < 4; ++v) {
        float u0 = a0[v] + bv0[v];
        float u1 = a1[v] + bv1[v];
        const bool d0 = diag0 && (lg * 4 + v == lr);
        const bool d1 = diag1 && (lg * 4 + v == lr);
        if (vis0 && !d0) u0 = 0.5f * u0 + 0.5f * xv0[v];
        if (vis1 && !d1) u1 = 0.5f * u1 + 0.5f * xv1[v];
        if (last) {
          if (d0) out[16 * g + lr] = u0;      // diag of U, pre-tanh
          if (d1) out[16 * g + lr] = u1;
        } else {
          float au0 = fabsf(u0), au1 = fabsf(u1);
          float e0 = __expf(-2.0f * au0), e1 = __expf(-2.0f * au1);
          float t0 = __fdividef(1.0f - e0, 1.0f + e0);
          float t1 = __fdividef(1.0f - e1, 1.0f + e1);
          pk0.h[v] = (_Float16)copysignf(t0, u0);
          pk1.h[v] = (_Float16)copysignf(t1, u1);
        }
      }

      if (!last) {
        const u64 ntag = (u64)(((t + 1) >> 1) & 1) * TAGM;
        u64 val0 = (pk0.u & ~TAGM) | ntag;
        u64 val1 = (pk1.u & ~TAGM) | ntag;
        char* wbuf = (char*)rbase + (size_t)((t + 1) & 1) * (128 * 1024)
                   + (size_t)g * 16384;
        __hip_atomic_store((u64*)(wbuf + so0 * 2), val0, __ATOMIC_RELAXED,
                           __HIP_MEMORY_SCOPE_AGENT);
        __hip_atomic_store((u64*)(wbuf + so1 * 2), val1, __ATOMIC_RELAXED,
                           __HIP_MEMORY_SCOPE_AGENT);
      }
    }
  }
}

extern "C" void kernel_launch(void* const* d_in, const int* in_sizes, int n_in,
                              void* d_out, int out_size, void* d_ws, size_t ws_size,
                              hipStream_t stream) {
  const float* X = (const float*)d_in[0];
  const float* W = (const float*)d_in[1];
  const float* b = (const float*)d_in[2];
  float* out = (float*)d_out;
  char* ws = (char*)d_ws;

  _Float16* WH = (_Float16*)(ws + WS_WH);
  _Float16* rb = (_Float16*)(ws + WS_R);

  // parity-0 r: zeros (valid r(0), tag 0).  parity-1: 0x0101 (tag=1, invalid
  // for tau(1)=0).
  hipMemsetAsync(ws + WS_R, 0x00, 128 * 1024, stream);
  hipMemsetAsync(ws + WS_R + 128 * 1024, 0x01, 128 * 1024, stream);
  rnn_prep<<<128, 256, 0, stream>>>(W, WH);
  rnn_main<<<32, 768, 0, stream>>>(X, b, WH, rb, out);
}

// Round 15
// 3529.366 us; speedup vs baseline: 1.5701x; 1.5701x over previous
//
#include <hip/hip_runtime.h>

#define TSTEPS 2048
#define VDIM 128
#define FDIM 512

typedef __attribute__((ext_vector_type(8))) _Float16 half8;
typedef __attribute__((ext_vector_type(4))) _Float16 half4;
typedef __attribute__((ext_vector_type(4))) float floatx4;
typedef unsigned long long u64;
typedef __attribute__((ext_vector_type(2))) unsigned long long u64x2;

// ws layout (bytes):
//   [0,512K)          WH: f16, A-frag order [chunk32][kk16][lane64][e8]
//   [1M,1M+128K)      r parity-0: [g16][kk16][slot32][e8] f16 (8KB/group)
//   [1M+128K,1M+256K) r parity-1: same
#define WS_WH 0
#define WS_R  (1024u * 1024u)

// Pre-swizzle W (fp32 row-major [j][k]) into A-frag order, single f16.
// A-frag (16x16x32 f16): lane l holds row (l&15), k = kk*32 + (l>>4)*8 + e.
__global__ __launch_bounds__(256) void rnn_prep(const float* __restrict__ W,
                                                _Float16* __restrict__ WH) {
  int tid = blockIdx.x * 256 + threadIdx.x;   // 32 chunks * 16 kk * 64 lanes
  int c  = tid >> 10;
  int kk = (tid >> 6) & 15;
  int l  = tid & 63;
  int j  = 16 * c + (l & 15);
  int k0 = kk * 32 + (l >> 4) * 8;
  const float* src = W + j * FDIM + k0;
  half8 vh;
#pragma unroll
  for (int e = 0; e < 8; ++e) vh[e] = (_Float16)src[e];
  *(half8*)(WH + (size_t)tid * 8) = vh;
}

// 64 WGs = 16 row-groups (g, 8 rows each) x 4 slices (s), 512 thr = 8 waves.
// Wave w owns feature chunk c = 4w+s (feats [16c,16c+16)), W in 64 regs.
// COMPACT exchange tile (R15): pad rows dropped -> 8KB/group,
// [kk16][slot32][e8] with slot = ksub*8 + row (row<8).  B-frag rows 8-15 of
// each MFMA are pad: fed by zero-initialized regs (exec-masked ds_reads),
// their output cols never stored.  Protocol unchanged (proven R4/R9):
// tag-in-data, tau(t)=(t>>1)&1 in every f16 LSB, single-asm-block poll
// (1 load + vmcnt(0)), LDS share, one barrier, IC write-through stores.
__global__ void __launch_bounds__(512, 1)
rnn_main(const float* __restrict__ X, const float* __restrict__ bvec,
         const _Float16* __restrict__ WH,
         _Float16* __restrict__ rbase, float* __restrict__ out) {
  __shared__ _Float16 lds[2][4096];           // 8KB per step-parity
  const int g  = blockIdx.x & 15;             // row-group: rows [8g, 8g+8)
  const int s  = blockIdx.x >> 4;             // slice 0..3
  const int w  = threadIdx.x >> 6;            // wave 0..7
  const int l  = threadIdx.x & 63;
  const int lr = l & 15;                      // D col = group-local row (pad if >=8)
  const int lg = l >> 4;
  const int c  = 4 * w + s;                   // feature chunk [16c,16c+16)
  const int jb = 16 * c + lg * 4;             // lane's 4 features
  const bool real = (lr < 8);                 // lane covers a real state row

  // persistent W fragments: 16 x half8 = 64 regs
  half8 wh[16];
#pragma unroll
  for (int kk = 0; kk < 16; ++kk) {
    wh[kk] = ((const half8*)WH)[(c * 16 + kk) * 64 + l];
    asm volatile("" : "+v"(wh[kk]));
  }

  const floatx4 bv = *(const floatx4*)(bvec + jb);
  const bool vis = (c < 8);                   // feats < 128
  const bool diagHere = (c == (g >> 1));
  const int dj = ((g & 1) << 3) + lr;         // diag feature's j&15 (real lanes)
  const u64 TAGM = 0x0001000100010001ULL;

  // poll: wave w owns compact kk-chunks 2w,2w+1 = bytes [w*1024, w*1024+1024)
  const int pcB = w * 1024 + l * 16;
  // producer store offset (bytes) into compact tile, for lane's 4 feats:
  //   kk = jb>>5, q = (jb>>3)&3, slot = q*8 + lr, byte = (jb&7)*2
  const int soB = ((jb >> 5) << 9) + ((((jb >> 3) & 3) << 3) + lr) * 16
                + ((jb & 7) << 1);
  // consumer B-frag read offset (real lanes): kk*512 + (lg*8+lr)*16
  const int roB = ((lg << 3) + lr) << 4;

  // B-frag registers: zero-init once; pad lanes keep zeros forever
  half8 bfr[16];
#pragma unroll
  for (int kk = 0; kk < 16; ++kk) { half8 z{}; bfr[kk] = z; }

  int budget = 4000000;

  for (int t = 0; t < TSTEPS; ++t) {
    // ---- poll own 1KB (2 compact chunks): ONE asm block (load + vmcnt(0)),
    // the only robust HIP-level pattern (R6/R11 lessons); drains prior stores
    const char* p0 = (const char*)rbase + (size_t)(t & 1) * (128 * 1024)
                   + (size_t)g * 8192 + pcB;
    const int wantbit = (t >> 1) & 1;
    u64x2 f0;
    for (;;) {
      asm volatile(
        "global_load_dwordx4 %0, %1, off sc0 sc1\n\t"
        "s_waitcnt vmcnt(0)"
        : "=&v"(f0) : "v"(p0) : "memory");
      int ok;
      if (wantbit) { u64 m = f0[0] & f0[1]; ok = ((~m) & TAGM) == 0; }
      else         { u64 m = f0[0] | f0[1]; ok = (m & TAGM) == 0; }
      if (__all(ok)) break;
      if (--budget < 0) break;
    }

    // ---- stage into LDS (compact, contiguous, conflict-free)
    char* lp = (char*)lds[t & 1];
    *(u64x2*)(lp + pcB) = f0;
    __syncthreads();

    // X row load after the barrier: overlaps B-frag reads / MFMA
    floatx4 xv = {0.f, 0.f, 0.f, 0.f};
    if (vis) xv = *(const floatx4*)(X + t * VDIM + jb);

    // ---- exec-masked B-frag reads: real lanes only (half return data)
    if (real) {
#pragma unroll
      for (int kk = 0; kk < 16; ++kk)
        bfr[kk] = *(const half8*)(lp + kk * 512 + roB);
    }

    // ---- MFMA: D[j][i] = sum_k W[j,k] r[i,k]; 2 accumulator chains
    floatx4 a0 = {0.f,0.f,0.f,0.f}, a1 = {0.f,0.f,0.f,0.f};
#pragma unroll
    for (int kk = 0; kk < 16; kk += 2) {
      a0 = __builtin_amdgcn_mfma_f32_16x16x32_f16(wh[kk],     bfr[kk],     a0, 0, 0, 0);
      a1 = __builtin_amdgcn_mfma_f32_16x16x32_f16(wh[kk + 1], bfr[kk + 1], a1, 0, 0, 0);
    }

    // ---- epilogue: combine, blend, tanh, tag, publish r(t+1) (real lanes)
    const bool last = (t == TSTEPS - 1);
    union { half4 h; u64 u; } pk; pk.u = 0;
#pragma unroll
    for (int v = 0; v < 4; ++v) {
      float u = a0[v] + a1[v] + bv[v];
      const bool isdiag = diagHere && real && (lg * 4 + v == dj);
      if (vis && !isdiag) u = 0.5f * u + 0.5f * xv[v];
      if (last) {
        if (isdiag) out[8 * g + lr] = u;      // diag of U, pre-tanh
      } else {
        float au = fabsf(u);
        float e2 = __expf(-2.0f * au);
        float th = __fdividef(1.0f - e2, 1.0f + e2);
        pk.h[v] = (_Float16)copysignf(th, u);
      }
    }

    if (!last && real) {
      const u64 ntag = (u64)(((t + 1) >> 1) & 1) * TAGM;
      u64 val = (pk.u & ~TAGM) | ntag;
      char* wbuf = (char*)rbase + (size_t)((t + 1) & 1) * (128 * 1024)
                 + (size_t)g * 8192;
      __hip_atomic_store((u64*)(wbuf + soB), val, __ATOMIC_RELAXED,
                         __HIP_MEMORY_SCOPE_AGENT);
    }
  }
}

extern "C" void kernel_launch(void* const* d_in, const int* in_sizes, int n_in,
                              void* d_out, int out_size, void* d_ws, size_t ws_size,
                              hipStream_t stream) {
  const float* X = (const float*)d_in[0];
  const float* W = (const float*)d_in[1];
  const float* b = (const float*)d_in[2];
  float* out = (float*)d_out;
  char* ws = (char*)d_ws;

  _Float16* WH = (_Float16*)(ws + WS_WH);
  _Float16* rb = (_Float16*)(ws + WS_R);

  // parity-0 r: zeros (valid r(0)=0, tag 0).  parity-1: 0x0101 (tag=1,
  // invalid for tau(1)=0).  Compact tiles: 128KB per parity.
  hipMemsetAsync(ws + WS_R, 0x00, 128 * 1024, stream);
  hipMemsetAsync(ws + WS_R + 128 * 1024, 0x01, 128 * 1024, stream);
  rnn_prep<<<128, 256, 0, stream>>>(W, WH);
  rnn_main<<<64, 512, 0, stream>>>(X, b, WH, rb, out);
}

// Round 16
// 3089.920 us; speedup vs baseline: 1.7934x; 1.1422x over previous
//
#include <hip/hip_runtime.h>

#define TSTEPS 2048
#define VDIM 128
#define FDIM 512

typedef __attribute__((ext_vector_type(8))) _Float16 half8;
typedef __attribute__((ext_vector_type(4))) _Float16 half4;
typedef __attribute__((ext_vector_type(4))) float floatx4;
typedef unsigned long long u64;
typedef __attribute__((ext_vector_type(2))) unsigned long long u64x2;

// ws layout (bytes):
//   [0,512K)        WH: f16, A-frag order [chunk32][kk16][lane64][e8]
//   [1M,1M+128K)    r parity-0: [g8][kk16][lane64][e8] f16 (16KB/group)
//   [1M+128K,+256K) r parity-1: same
#define WS_WH 0
#define WS_R  (1024u * 1024u)

// Pre-swizzle W (fp32 row-major [j][k]) into A-frag order, single f16.
// A-frag (16x16x32 f16): lane l holds row (l&15), k = kk*32 + (l>>4)*8 + e.
__global__ __launch_bounds__(256) void rnn_prep(const float* __restrict__ W,
                                                _Float16* __restrict__ WH) {
  int tid = blockIdx.x * 256 + threadIdx.x;   // 32 chunks * 16 kk * 64 lanes
  int c  = tid >> 10;
  int kk = (tid >> 6) & 15;
  int l  = tid & 63;
  int j  = 16 * c + (l & 15);
  int k0 = kk * 32 + (l >> 4) * 8;
  const float* src = W + j * FDIM + k0;
  half8 vh;
#pragma unroll
  for (int e = 0; e < 8; ++e) vh[e] = (_Float16)src[e];
  *(half8*)(WH + (size_t)tid * 8) = vh;
}

// 32 WGs = 8 row-groups (g) x 4 slices (s), 512 thr = 8 waves, wave owns
// chunk c = 4w+s (features [16c,16c+16)), W resident in 64 regs (AGPR-side
// of the unified file; R10 falsified the spill theory via FETCH arithmetic).
// Protocol (proven R4/R9): tag-in-data, tau(t)=(t>>1)&1 in every f16 LSB,
// each wave polls only its own 2 exchange chunks via ONE asm block
// (loads + vmcnt(0) — the only robust HIP-level pattern, R6/R11 lessons),
// LDS share, one barrier, IC write-through stores.
// R16 = R9 + micro-trims: 4 MFMA accumulator chains, 7-op tanh.
__global__ void __launch_bounds__(512, 1)
rnn_main(const float* __restrict__ X, const float* __restrict__ bvec,
         const _Float16* __restrict__ WH,
         _Float16* __restrict__ rbase, float* __restrict__ out) {
  __shared__ _Float16 lds[2][8192];           // 16KB per step-parity
  const int g  = blockIdx.x & 7;
  const int s  = blockIdx.x >> 3;
  const int w  = threadIdx.x >> 6;
  const int l  = threadIdx.x & 63;
  const int lr = l & 15;                      // D col = group-local state row
  const int lg = l >> 4;
  const int c  = 4 * w + s;                   // W chunk = feats [16c,16c+16)
  const int jb = 16 * c + lg * 4;             // this lane's 4 features

  // persistent W fragments: 16 x half8 = 64 regs
  half8 wh[16];
#pragma unroll
  for (int kk = 0; kk < 16; ++kk) {
    wh[kk] = ((const half8*)WH)[(c * 16 + kk) * 64 + l];
    asm volatile("" : "+v"(wh[kk]));
  }

  const floatx4 bv = *(const floatx4*)(bvec + jb);
  const bool vis = (16 * c < 128);
  const bool diagHere = (c == g);
  const u64 TAGM = 0x0001000100010001ULL;

  // poll region: wave w owns exchange chunks 2w, 2w+1; 16B/lane each
  const int pc = (2 * w) * 1024 + l * 16;
  // produced half4 frag offset (halves): kk*512 + (sub*16+lr)*8 + (jb&7)
  const int so = ((jb >> 5) << 9) + ((((jb >> 3) & 3) << 4) + lr) * 8 + (jb & 7);

  int budget = 4000000;

  for (int t = 0; t < TSTEPS; ++t) {
    floatx4 xv = {0.f, 0.f, 0.f, 0.f};
    if (vis) xv = *(const floatx4*)(X + t * VDIM + jb);
    asm volatile("" : "+v"(xv));              // issue X before the polls

    // ---- poll own 2 chunks (IC-coherent 16B loads, single asm block)
    const char* rb = (const char*)rbase + (size_t)(t & 1) * (128 * 1024)
                   + (size_t)g * 16384;
    const u64 want = (u64)((t >> 1) & 1) * TAGM;
    u64 v0, v1, v2, v3;
    for (;;) {
      u64x2 A, B;
      asm volatile("global_load_dwordx4 %0, %2, off sc0 sc1\n\t"
                   "global_load_dwordx4 %1, %3, off sc0 sc1\n\t"
                   "s_waitcnt vmcnt(0)"
                   : "=&v"(A), "=&v"(B)
                   : "v"(rb + pc), "v"(rb + pc + 1024)
                   : "memory");
      v0 = A[0]; v1 = A[1]; v2 = B[0]; v3 = B[1];
      int ok = ((v0 & TAGM) == want) & ((v1 & TAGM) == want) &
               ((v2 & TAGM) == want) & ((v3 & TAGM) == want);
      if (__all(ok)) break;
      if (--budget < 0) break;
    }

    // ---- stage into LDS (linear frag order), share via one barrier
    char* lp = (char*)lds[t & 1];
    { ulonglong2 a; a.x = v0; a.y = v1; *(ulonglong2*)(lp + pc) = a; }
    { ulonglong2 a; a.x = v2; a.y = v3; *(ulonglong2*)(lp + pc + 1024) = a; }
    __syncthreads();

    // ---- MFMA: D[j][i] = sum_k W[j,k] r[i,k]; 4 accumulator chains
    floatx4 a0 = {0.f,0.f,0.f,0.f}, a1 = {0.f,0.f,0.f,0.f};
    floatx4 a2 = {0.f,0.f,0.f,0.f}, a3 = {0.f,0.f,0.f,0.f};
#pragma unroll
    for (int kk = 0; kk < 16; kk += 4) {
      half8 b0 = *(const half8*)(lp + kk * 1024 + l * 16);
      half8 b1 = *(const half8*)(lp + (kk + 1) * 1024 + l * 16);
      half8 b2 = *(const half8*)(lp + (kk + 2) * 1024 + l * 16);
      half8 b3 = *(const half8*)(lp + (kk + 3) * 1024 + l * 16);
      a0 = __builtin_amdgcn_mfma_f32_16x16x32_f16(wh[kk],     b0, a0, 0, 0, 0);
      a1 = __builtin_amdgcn_mfma_f32_16x16x32_f16(wh[kk + 1], b1, a1, 0, 0, 0);
      a2 = __builtin_amdgcn_mfma_f32_16x16x32_f16(wh[kk + 2], b2, a2, 0, 0, 0);
      a3 = __builtin_amdgcn_mfma_f32_16x16x32_f16(wh[kk + 3], b3, a3, 0, 0, 0);
    }

    // ---- epilogue: combine, blend, tanh (7-op), tag, publish r(t+1)
    const bool last = (t == TSTEPS - 1);
    union { half4 h; u64 u; } pk; pk.u = 0;
#pragma unroll
    for (int v = 0; v < 4; ++v) {
      float u = (a0[v] + a1[v]) + (a2[v] + a3[v]) + bv[v];
      const bool isdiag = diagHere && (lg * 4 + v == lr);
      if (vis && !isdiag) u = 0.5f * u + 0.5f * xv[v];
      if (last) {
        if (isdiag) out[16 * g + lr] = u;     // diag of U, pre-tanh
      } else {
        // tanh(u) = copysign(1 - 2/(1 + e^{2|u|}), u)
        float au = fabsf(u);
        float e2 = __expf(2.0f * au);
        float th = fmaf(-2.0f, __frcp_rn(1.0f + e2), 1.0f);
        pk.h[v] = (_Float16)copysignf(th, u);
      }
    }

    if (!last) {
      const u64 ntag = (u64)(((t + 1) >> 1) & 1) * TAGM;
      u64 val = (pk.u & ~TAGM) | ntag;
      char* wbuf = (char*)rbase + (size_t)((t + 1) & 1) * (128 * 1024)
                 + (size_t)g * 16384;
      __hip_atomic_store((u64*)(wbuf + so * 2), val, __ATOMIC_RELAXED,
                         __HIP_MEMORY_SCOPE_AGENT);
    }
  }
}

extern "C" void kernel_launch(void* const* d_in, const int* in_sizes, int n_in,
                              void* d_out, int out_size, void* d_ws, size_t ws_size,
                              hipStream_t stream) {
  const float* X = (const float*)d_in[0];
  const float* W = (const float*)d_in[1];
  const float* b = (const float*)d_in[2];
  float* out = (float*)d_out;
  char* ws = (char*)d_ws;

  _Float16* WH = (_Float16*)(ws + WS_WH);
  _Float16* rb = (_Float16*)(ws + WS_R);

  // parity-0 r: zeros (valid r(0), tag 0).  parity-1: 0x0101 (tag=1, invalid
  // for tau(1)=0).
  hipMemsetAsync(ws + WS_R, 0x00, 128 * 1024, stream);
  hipMemsetAsync(ws + WS_R + 128 * 1024, 0x01, 128 * 1024, stream);
  rnn_prep<<<128, 256, 0, stream>>>(W, WH);
  rnn_main<<<32, 512, 0, stream>>>(X, b, WH, rb, out);
}

// Round 17
// 3009.476 us; speedup vs baseline: 1.8413x; 1.0267x over previous
//
#include <hip/hip_runtime.h>

#define TSTEPS 2048
#define VDIM 128
#define FDIM 512

typedef __attribute__((ext_vector_type(8))) _Float16 half8;
typedef __attribute__((ext_vector_type(4))) _Float16 half4;
typedef __attribute__((ext_vector_type(4))) float floatx4;
typedef unsigned long long u64;
typedef __attribute__((ext_vector_type(2))) unsigned long long u64x2;

// ws layout (bytes):
//   [0,512K)        WH: f16, A-frag order [chunk32][kk16][lane64][e8]
//   [1M,1M+128K)    r parity-0: [g8][kk16][lane64][e8] f16 (16KB/group)
//   [1M+128K,+256K) r parity-1: same
#define WS_WH 0
#define WS_R  (1024u * 1024u)

// Pre-swizzle W (fp32 row-major [j][k]) into A-frag order, single f16.
// A-frag (16x16x32 f16): lane l holds row (l&15), k = kk*32 + (l>>4)*8 + e.
__global__ __launch_bounds__(256) void rnn_prep(const float* __restrict__ W,
                                                _Float16* __restrict__ WH) {
  int tid = blockIdx.x * 256 + threadIdx.x;   // 32 chunks * 16 kk * 64 lanes
  int c  = tid >> 10;
  int kk = (tid >> 6) & 15;
  int l  = tid & 63;
  int j  = 16 * c + (l & 15);
  int k0 = kk * 32 + (l >> 4) * 8;
  const float* src = W + j * FDIM + k0;
  half8 vh;
#pragma unroll
  for (int e = 0; e < 8; ++e) vh[e] = (_Float16)src[e];
  *(half8*)(WH + (size_t)tid * 8) = vh;
}

// 32 WGs = 8 row-groups (g) x 4 slices (s), 512 thr = 8 waves, wave owns
// chunk c = 4w+s (features [16c,16c+16)), W resident in 64 regs.
// R4-proven protocol: tag-in-data (tau(t)=(t>>1)&1 in every f16 LSB), each
// wave polls only its own 2 exchange chunks via IC-coherent loads (ONE asm
// block: loads + vmcnt(0) — the only robust HIP-level pattern), shares
// through LDS, one barrier, MFMA from LDS, store r(t+1) write-through.
// FINAL (== R9, measured optimum 3011 us): 10 structural variants lost to
// this shape; residual is the IC coherence round-trip latency x 2048 steps.
__global__ void __launch_bounds__(512, 2)
rnn_main(const float* __restrict__ X, const float* __restrict__ bvec,
         const _Float16* __restrict__ WH,
         _Float16* __restrict__ rbase, float* __restrict__ out) {
  __shared__ _Float16 lds[2][8192];           // 16KB per step-parity
  const int g  = blockIdx.x & 7;
  const int s  = blockIdx.x >> 3;
  const int w  = threadIdx.x >> 6;
  const int l  = threadIdx.x & 63;
  const int lr = l & 15;                      // D col = group-local state row
  const int lg = l >> 4;
  const int c  = 4 * w + s;                   // W chunk = feats [16c,16c+16)
  const int jb = 16 * c + lg * 4;             // this lane's 4 features

  // persistent W fragments: 16 x half8 = 64 regs, pinned
  half8 wh[16];
#pragma unroll
  for (int kk = 0; kk < 16; ++kk) {
    wh[kk] = ((const half8*)WH)[(c * 16 + kk) * 64 + l];
    asm volatile("" : "+v"(wh[kk]));
  }

  const floatx4 bv = *(const floatx4*)(bvec + jb);
  const bool vis = (16 * c < 128);
  const bool diagHere = (c == g);
  const u64 TAGM = 0x0001000100010001ULL;

  // poll region: wave w owns exchange chunks 2w, 2w+1; 16B/lane each
  const int pc = (2 * w) * 1024 + l * 16;
  // produced half4 frag offset (halves): kk*512 + (sub*16+lr)*8 + (jb&7)
  const int so = ((jb >> 5) << 9) + ((((jb >> 3) & 3) << 4) + lr) * 8 + (jb & 7);

  int budget = 4000000;

  for (int t = 0; t < TSTEPS; ++t) {
    floatx4 xv = {0.f, 0.f, 0.f, 0.f};
    if (vis) xv = *(const floatx4*)(X + t * VDIM + jb);
    asm volatile("" : "+v"(xv));              // issue X before the polls

    // ---- poll own 2 chunks (IC-coherent 16B loads, single asm block)
    const char* rb = (const char*)rbase + (size_t)(t & 1) * (128 * 1024)
                   + (size_t)g * 16384;
    const u64 want = (u64)((t >> 1) & 1) * TAGM;
    u64 v0, v1, v2, v3;
    for (;;) {
      u64x2 A, B;
      asm volatile("global_load_dwordx4 %0, %2, off sc0 sc1\n\t"
                   "global_load_dwordx4 %1, %3, off sc0 sc1\n\t"
                   "s_waitcnt vmcnt(0)"
                   : "=&v"(A), "=&v"(B)
                   : "v"(rb + pc), "v"(rb + pc + 1024)
                   : "memory");
      v0 = A[0]; v1 = A[1]; v2 = B[0]; v3 = B[1];
      int ok = ((v0 & TAGM) == want) & ((v1 & TAGM) == want) &
               ((v2 & TAGM) == want) & ((v3 & TAGM) == want);
      if (__all(ok)) break;
      if (--budget < 0) break;
    }

    // ---- stage into LDS (linear frag order), share via one barrier
    char* lp = (char*)lds[t & 1];
    { ulonglong2 a; a.x = v0; a.y = v1; *(ulonglong2*)(lp + pc) = a; }
    { ulonglong2 a; a.x = v2; a.y = v3; *(ulonglong2*)(lp + pc + 1024) = a; }
    __syncthreads();

    // ---- MFMA: D[j][i] = sum_k W[j,k] r[i,k]; 2 acc chains (even/odd kk)
    floatx4 a0 = {0.f,0.f,0.f,0.f}, a1 = {0.f,0.f,0.f,0.f};
#pragma unroll
    for (int kk = 0; kk < 16; kk += 2) {
      half8 b0 = *(const half8*)(lp + kk * 1024 + l * 16);
      half8 b1 = *(const half8*)(lp + (kk + 1) * 1024 + l * 16);
      a0 = __builtin_amdgcn_mfma_f32_16x16x32_f16(wh[kk],     b0, a0, 0, 0, 0);
      a1 = __builtin_amdgcn_mfma_f32_16x16x32_f16(wh[kk + 1], b1, a1, 0, 0, 0);
    }

    // ---- epilogue: combine, blend, tanh, tag, publish r(t+1)
    const bool last = (t == TSTEPS - 1);
    union { half4 h; u64 u; } pk; pk.u = 0;
#pragma unroll
    for (int v = 0; v < 4; ++v) {
      float u = a0[v] + a1[v] + bv[v];
      const bool isdiag = diagHere && (lg * 4 + v == lr);
      if (vis && !isdiag) u = 0.5f * u + 0.5f * xv[v];
      if (last) {
        if (isdiag) out[16 * g + lr] = u;     // diag of U, pre-tanh
      } else {
        float au = fabsf(u);
        float e2 = __expf(-2.0f * au);
        float th = __fdividef(1.0f - e2, 1.0f + e2);
        pk.h[v] = (_Float16)copysignf(th, u);
      }
    }

    if (!last) {
      const u64 ntag = (u64)(((t + 1) >> 1) & 1) * TAGM;
      u64 val = (pk.u & ~TAGM) | ntag;
      char* wbuf = (char*)rbase + (size_t)((t + 1) & 1) * (128 * 1024)
                 + (size_t)g * 16384;
      __hip_atomic_store((u64*)(wbuf + so * 2), val, __ATOMIC_RELAXED,
                         __HIP_MEMORY_SCOPE_AGENT);
    }
  }
}

extern "C" void kernel_launch(void* const* d_in, const int* in_sizes, int n_in,
                              void* d_out, int out_size, void* d_ws, size_t ws_size,
                              hipStream_t stream) {
  const float* X = (const float*)d_in[0];
  const float* W = (const float*)d_in[1];
  const float* b = (const float*)d_in[2];
  float* out = (float*)d_out;
  char* ws = (char*)d_ws;

  _Float16* WH = (_Float16*)(ws + WS_WH);
  _Float16* rb = (_Float16*)(ws + WS_R);

  // parity-0 r: zeros (valid r(0), tag 0).  parity-1: 0x0101 (tag=1, invalid
  // for tau(1)=0).
  hipMemsetAsync(ws + WS_R, 0x00, 128 * 1024, stream);
  hipMemsetAsync(ws + WS_R + 128 * 1024, 0x01, 128 * 1024, stream);
  rnn_prep<<<128, 256, 0, stream>>>(W, WH);
  rnn_main<<<32, 512, 0, stream>>>(X, b, WH, rb, out);
}